// Round 15
// baseline (108.196 us; speedup 1.0000x reference)
//
#include <hip/hip_runtime.h>
#include <hip/hip_bf16.h>

#define B_    4
#define S_    2048
#define HID_  512
#define NH_   8
#define HD_   64
#define MAXREL 512
#define M_    (B_ * S_)   // 8192 tokens

#define LOG2E 1.44269504f
#define SCALE_Q (0.125f * LOG2E)   // folded into Q at projection time

typedef __attribute__((ext_vector_type(8))) short bf8;            // 8 bf16 (MFMA A/B frag)
typedef __attribute__((ext_vector_type(4))) float f4;             // 16x16 C/D frag
typedef __attribute__((ext_vector_type(16))) float f16f;          // 32x32 C/D frag

static __device__ __forceinline__ unsigned short f2bf(float f) {
    union { float f; unsigned int u; } v; v.f = f;
    unsigned int u = v.u;
    unsigned int r = (u + 0x7FFFu + ((u >> 16) & 1u)) >> 16;   // round-nearest-even
    return (unsigned short)r;
}

static __device__ __forceinline__ float ex2(float x) {   // raw v_exp_f32 (base-2)
    float r; asm("v_exp_f32 %0, %1" : "=v"(r) : "v"(x)); return r;
}

// async global->LDS, 16B per lane; dest = wave-uniform base + lane*16 (linear)
static __device__ __forceinline__ void gload16(const void* g, void* l) {
    __builtin_amdgcn_global_load_lds(
        (const __attribute__((address_space(1))) unsigned int*)g,
        (__attribute__((address_space(3))) unsigned int*)l, 16, 0, 0);
}

static __device__ __forceinline__ bf8 mkbf8(unsigned a, unsigned b, unsigned c, unsigned d) {
    uint4 u = make_uint4(a, b, c, d);
    return *(bf8*)&u;
}

#define MFMA16(a, b, c) __builtin_amdgcn_mfma_f32_16x16x32_bf16((a), (b), (c), 0, 0, 0)
#define MFMA32(a, b, c) __builtin_amdgcn_mfma_f32_32x32x16_bf16((a), (b), (c), 0, 0, 0)

// ---------------- cast hidden_states fp32 -> bf16 + mask bit-pack (block 0) ----------------
__global__ void k_cast_hs(const float* __restrict__ src, unsigned short* __restrict__ dst, int n4,
                          const float* __restrict__ mask, unsigned* __restrict__ maskbits) {
    int i = blockIdx.x * blockDim.x + threadIdx.x;
    if (i < n4) {
        float4 v = ((const float4*)src)[i];
        ushort4 o;
        o.x = f2bf(v.x); o.y = f2bf(v.y); o.z = f2bf(v.z); o.w = f2bf(v.w);
        ((ushort4*)dst)[i] = o;
    }
    if (blockIdx.x == 0 && threadIdx.x < 256) {
        const int t = threadIdx.x;
        const int b = t >> 6, wd = t & 63;
        unsigned bits = 0;
        #pragma unroll
        for (int j = 0; j < 32; ++j)
            bits |= (mask[b * S_ + wd * 32 + j] > 0.5f ? 1u : 0u) << j;
        maskbits[t] = bits;
    }
}

// ---------------- transpose + cast 4 weights (LDS 32x32 tiles) ----------------
__global__ void k_transpose_w4(const float* __restrict__ W0, const float* __restrict__ W1,
                               const float* __restrict__ W2, const float* __restrict__ W3,
                               unsigned short* __restrict__ T0, unsigned short* __restrict__ T1,
                               unsigned short* __restrict__ T2, unsigned short* __restrict__ T3) {
    __shared__ float tile[32][33];
    const int z = blockIdx.z;
    const float* W = (z == 0) ? W0 : (z == 1) ? W1 : (z == 2) ? W2 : W3;
    unsigned short* T = (z == 0) ? T0 : (z == 1) ? T1 : (z == 2) ? T2 : T3;
    const int tx = threadIdx.x & 31, ty = threadIdx.x >> 5;   // 256 thr
    const int n0 = blockIdx.x * 32, k0 = blockIdx.y * 32;
    #pragma unroll
    for (int i = 0; i < 4; ++i)
        tile[ty + i * 8][tx] = W[(size_t)(k0 + ty + i * 8) * HID_ + n0 + tx];
    __syncthreads();
    #pragma unroll
    for (int i = 0; i < 4; ++i)
        T[(size_t)(n0 + ty + i * 8) * HID_ + k0 + tx] = f2bf(tile[tx][ty + i * 8]);
}

// ---------------- fused QKV GEMM: 128x128 tile, dbuf LDS via global_load_lds ----------------
__global__ __launch_bounds__(256, 3) void k_gemm_qkv(
    const unsigned short* __restrict__ Abf,
    const unsigned short* __restrict__ Wqt, const unsigned short* __restrict__ Wkt,
    const unsigned short* __restrict__ Wvt,
    const float* __restrict__ bq, const float* __restrict__ bk, const float* __restrict__ bv,
    unsigned short* __restrict__ Q, unsigned short* __restrict__ K, unsigned short* __restrict__ Vt)
{
    __shared__ unsigned short Al[2][128 * 32];
    __shared__ unsigned short Bl[2][128 * 32];

    const int t = threadIdx.x;
    const int lane = t & 63, w = t >> 6;
    const int lr = lane & 15, lg = lane >> 4;
    const int wr = w >> 1, wc = w & 1;

    const int m0 = blockIdx.x * 128;
    const int ng = blockIdx.y * 128;
    const int z = ng >> 9;
    const int n0 = ng & 511;
    const unsigned short* Wt = (z == 0) ? Wqt : ((z == 1) ? Wkt : Wvt);
    const float* bias = (z == 0) ? bq : ((z == 1) ? bk : bv);
    const float osc = (z == 0) ? SCALE_Q : 1.0f;

    const int srow = t >> 2;
    const int sc = (((t & 3) ^ ((srow >> 1) & 3))) * 8;     // swizzled source col
    const unsigned short* Ag0 = &Abf[(size_t)(m0 + srow) * HID_ + sc];
    const unsigned short* Ag1 = &Abf[(size_t)(m0 + 64 + srow) * HID_ + sc];
    const unsigned short* Bg0 = &Wt[(size_t)(n0 + srow) * HID_ + sc];
    const unsigned short* Bg1 = &Wt[(size_t)(n0 + 64 + srow) * HID_ + sc];
    char* dA0 = (char*)&Al[0][0] + w * 1024;
    char* dB0 = (char*)&Bl[0][0] + w * 1024;

    const int fx = (lr >> 1) & 3;
    int aoff[4], boff[4];
    #pragma unroll
    for (int i = 0; i < 4; ++i) {
        aoff[i] = (wr * 64 + i * 16 + lr) * 32 + ((lg ^ fx) * 8);
        boff[i] = (wc * 64 + i * 16 + lr) * 32 + ((lg ^ fx) * 8);
    }

    gload16(Ag0, dA0);
    gload16(Ag1, dA0 + 4096);
    gload16(Bg0, dB0);
    gload16(Bg1, dB0 + 4096);
    __syncthreads();

    f4 acc[4][4] = {};
    for (int kt = 0; kt < 16; ++kt) {
        const int cur = kt & 1;
        if (kt < 15) {
            const int ko = (kt + 1) * 32;
            const int bo = (cur ^ 1) * 8192;
            gload16(Ag0 + ko, dA0 + bo);
            gload16(Ag1 + ko, dA0 + bo + 4096);
            gload16(Bg0 + ko, dB0 + bo);
            gload16(Bg1 + ko, dB0 + bo + 4096);
        }
        bf8 af[4], bf_[4];
        #pragma unroll
        for (int i = 0; i < 4; ++i) {
            af[i]  = *(const bf8*)&Al[cur][aoff[i]];
            bf_[i] = *(const bf8*)&Bl[cur][boff[i]];
        }
        #pragma unroll
        for (int mi = 0; mi < 4; ++mi)
            #pragma unroll
            for (int ni = 0; ni < 4; ++ni)
                acc[mi][ni] = MFMA16(af[mi], bf_[ni], acc[mi][ni]);
        __syncthreads();
    }

    #pragma unroll
    for (int mi = 0; mi < 4; ++mi)
    #pragma unroll
    for (int ni = 0; ni < 4; ++ni) {
        const int col = n0 + wc * 64 + ni * 16 + lr;
        const int h = col >> 6, d = col & 63;
        const float bs = bias[col];
        const int row0 = m0 + wr * 64 + mi * 16 + lg * 4;
        const int b = row0 >> 11, s0 = row0 & 2047;
        if (z == 2) {
            ushort4 o;
            o.x = f2bf(acc[mi][ni][0] + bs);
            o.y = f2bf(acc[mi][ni][1] + bs);
            o.z = f2bf(acc[mi][ni][2] + bs);
            o.w = f2bf(acc[mi][ni][3] + bs);
            *(ushort4*)&Vt[(((size_t)(b * NH_ + h)) * HD_ + d) * S_ + s0] = o;
        } else {
            unsigned short* dst = (z == 0) ? Q : K;
            #pragma unroll
            for (int r = 0; r < 4; ++r) {
                float v = (acc[mi][ni][r] + bs) * osc;
                dst[(((size_t)(b * NH_ + h)) * S_ + s0 + r) * HD_ + d] = f2bf(v);
            }
        }
    }
}

// ---------------- output projection GEMM: 128x128 tile, 512 threads ----------------
__global__ __launch_bounds__(512) void k_gemm_out(
    const unsigned short* __restrict__ Abf,
    const unsigned short* __restrict__ Wot,
    const float* __restrict__ bo,
    float* __restrict__ out)
{
    __shared__ unsigned short Al[2][128 * 32];
    __shared__ unsigned short Bl[2][128 * 32];

    const int t = threadIdx.x;
    const int lane = t & 63, w = t >> 6;          // 8 waves, 2x4
    const int lr = lane & 15, lg = lane >> 4;
    const int wr = w >> 2, wc = w & 3;

    const int m0 = blockIdx.x * 128;
    const int n0 = blockIdx.y * 128;

    const int srow = t >> 2;
    const int sc = (((t & 3) ^ ((srow >> 1) & 3))) * 8;
    const unsigned short* Ag = &Abf[(size_t)(m0 + srow) * HID_ + sc];
    const unsigned short* Bg = &Wot[(size_t)(n0 + srow) * HID_ + sc];
    char* dA = (char*)&Al[0][0] + w * 1024;
    char* dB = (char*)&Bl[0][0] + w * 1024;

    const int fx = (lr >> 1) & 3;
    int aoff[4], boff[2];
    #pragma unroll
    for (int i = 0; i < 4; ++i)
        aoff[i] = (wr * 64 + i * 16 + lr) * 32 + ((lg ^ fx) * 8);
    #pragma unroll
    for (int i = 0; i < 2; ++i)
        boff[i] = (wc * 32 + i * 16 + lr) * 32 + ((lg ^ fx) * 8);

    gload16(Ag, dA);
    gload16(Bg, dB);
    __syncthreads();

    f4 acc[4][2] = {};
    for (int kt = 0; kt < 16; ++kt) {
        const int cur = kt & 1;
        if (kt < 15) {
            const int ko = (kt + 1) * 32;
            const int bo_ = (cur ^ 1) * 8192;
            gload16(Ag + ko, dA + bo_);
            gload16(Bg + ko, dB + bo_);
        }
        bf8 af[4], bf_[2];
        #pragma unroll
        for (int i = 0; i < 4; ++i) af[i] = *(const bf8*)&Al[cur][aoff[i]];
        #pragma unroll
        for (int i = 0; i < 2; ++i) bf_[i] = *(const bf8*)&Bl[cur][boff[i]];
        #pragma unroll
        for (int mi = 0; mi < 4; ++mi)
            #pragma unroll
            for (int ni = 0; ni < 2; ++ni)
                acc[mi][ni] = MFMA16(af[mi], bf_[ni], acc[mi][ni]);
        __syncthreads();
    }

    #pragma unroll
    for (int mi = 0; mi < 4; ++mi)
    #pragma unroll
    for (int ni = 0; ni < 2; ++ni) {
        const int col = n0 + wc * 32 + ni * 16 + lr;
        const float bs = bo[col];
        const int row0 = m0 + wr * 64 + mi * 16 + lg * 4;
        #pragma unroll
        for (int r = 0; r < 4; ++r)
            out[(size_t)(row0 + r) * HID_ + col] = acc[mi][ni][r] + bs;
    }
}

// ---------------- flash attention: 8 waves = 4 q-groups x 2 kv-halves, mfma 32x32x16.
//   Pair-ILP: 16 bodies x 2 KV-tiles; 4-buffer KV; one merged softmax decision per pair;
//   non-speculative exp (check first). Mask bitmask fast path; LDS pair-merge epilogue. ----------------
__global__ __launch_bounds__(512, 4) void k_flash(
    const unsigned short* __restrict__ Q, const unsigned short* __restrict__ K,
    const unsigned short* __restrict__ Vt,
    const float* __restrict__ rel_table, const unsigned* __restrict__ maskbits,
    unsigned short* __restrict__ ctx)
{
    __shared__ unsigned short KV[4][8192];   // per buf: [0,4096) ushorts K, [4096,8192) V
    __shared__ float Tw[1216];               // bias window, rel in [-605,605], pre-clipped, *log2e

    const int t = threadIdx.x;
    const int lane = t & 63, w = t >> 6;     // 8 waves
    const int q = lane & 31, hi = lane >> 5;
    const int g = w & 3, kvh = w >> 2;       // q-group, kv-half

    // bijective XCD swizzle: each XCD owns 4 complete (b,h) pairs
    const int flat = blockIdx.x;             // 0..511
    const int idx = flat >> 3;
    const int bh = (flat & 7) * 4 + (idx >> 4);
    const int qb = idx & 15;
    const int b = bh >> 3, h = bh & 7;
    const int q0 = qb * 128;

    // mask words: lane ti (<32) holds word for tile ti (this wave's kv-half)
    unsigned mword = 0xFFFFFFFFu;
    if (lane < 32) mword = maskbits[b * 64 + 2 * lane + kvh];

    for (int i = t; i < 1216; i += 512) {
        int r = i - 606;
        r = r < -MAXREL ? -MAXREL : (r > MAXREL ? MAXREL : r);
        Tw[i] = rel_table[(r + MAXREL) * NH_ + h] * LOG2E;
    }
    const float TbLo = rel_table[h] * LOG2E;                    // rel = -512
    const float TbHi = rel_table[2 * MAXREL * NH_ + h] * LOG2E; // rel = +512

    const unsigned short* Kb = K + (size_t)bh * S_ * HD_;
    const unsigned short* Vb = Vt + (size_t)bh * HD_ * S_;

    const int myq = q0 + g * 32 + q;
    const int qw = q0 + g * 32;
    bf8 qf[4];   // B-frag: col=q, k(d)=16s+8hi+j
    #pragma unroll
    for (int s = 0; s < 4; ++s)
        qf[s] = *(const bf8*)&Q[((size_t)bh * S_ + myq) * HD_ + s * 16 + hi * 8];

    // staging (512 thr): thread t -> row t>>3 (0..63), slot t&7; source col pre-swizzled
    const int srow = t >> 3, sslot = t & 7;
    const int sxor = (sslot ^ (srow & 7)) * 8;
    const size_t kb0 = (size_t)srow * HD_ + sxor;
    const size_t vb0 = (size_t)srow * S_ + sxor;
    const int woff = w * 1024;               // wave's linear 1KB chunk (8 rows x 128B)

    auto stage = [&](int kvt, int buf) {
        char* base = (char*)&KV[buf][0];
        gload16(&Kb[kb0 + (size_t)kvt * 64 * HD_], base + woff);
        gload16(&Vb[vb0 + (size_t)kvt * 64], base + 8192 + woff);
    };

    f16f ca0 = {}, ca1 = {};       // ctx^T partial: col=q, d = {0,32} + (reg&3)+8*(reg>>2)+4hi
    float m_s = -INFINITY, lsum = 0.f;

    // prologue: both pair-sets staged (pair0 -> bufs 0,1; pair1 -> bufs 2,3)
    stage(0, 0); stage(1, 1);
    stage(2, 2); stage(3, 3);
    asm volatile("s_waitcnt lgkmcnt(0)" ::: "memory");   // Tw ds_writes drained
    asm volatile("s_waitcnt vmcnt(4)" ::: "memory");     // pair0's 4 loads done
    __builtin_amdgcn_s_barrier();
    __builtin_amdgcn_sched_barrier(0);

    const int xq = q & 7;
    // Tw index: 606 + key - myq; key = kv0 + 32*kvh + 8m + 4hi + r
    const int jb0 = 606 + 32 * kvh + 4 * hi - q0 - g * 32 - q;   // + kv0 + 8m + r

    for (int p = 0; p < 16; ++p) {
        const int bs = (p & 1) * 2;
        const int kv0a = p * 128;
        const int kv0b = kv0a + 64;
        const int kvsa = kv0a + 32 * kvh;
        const int kvsb = kv0b + 32 * kvh;

        const unsigned short* Kta = &KV[bs][0];
        const unsigned short* Vta = &KV[bs][4096];
        const unsigned short* Ktb = &KV[bs + 1][0];
        const unsigned short* Vtb = &KV[bs + 1][4096];

        // ---- QK^T both tiles (8 independent MFMA32) ----
        f16f sa = {}, sb = {};
        __builtin_amdgcn_s_setprio(1);
        #pragma unroll
        for (int s = 0; s < 4; ++s) {
            const int ko = (32 * kvh + q) * 64 + (((2 * s + hi) ^ xq) * 8);
            bf8 kfa = *(const bf8*)&Kta[ko];
            bf8 kfb = *(const bf8*)&Ktb[ko];
            sa = MFMA32(kfa, qf[s], sa);
            sb = MFMA32(kfb, qf[s], sb);
        }
        __builtin_amdgcn_s_setprio(0);

        // ---- mask (rare slow path; scalar-uniform skip when all-attend) ----
        const unsigned mwa = __builtin_amdgcn_readlane(mword, 2 * p);
        const unsigned mwb = __builtin_amdgcn_readlane(mword, 2 * p + 1);
        if (mwa != 0xFFFFFFFFu) {
            #pragma unroll
            for (int m = 0; m < 4; ++m) {
                const unsigned tb = mwa >> (8 * m + 4 * hi);
                #pragma unroll
                for (int r = 0; r < 4; ++r)
                    sa[4 * m + r] += ((tb >> r) & 1) ? 0.f : -3.0e38f;
            }
        }
        if (mwb != 0xFFFFFFFFu) {
            #pragma unroll
            for (int m = 0; m < 4; ++m) {
                const unsigned tb = mwb >> (8 * m + 4 * hi);
                #pragma unroll
                for (int r = 0; r < 4; ++r)
                    sb[4 * m + r] += ((tb >> r) & 1) ? 0.f : -3.0e38f;
            }
        }

        // ---- bias + merged row max over both tiles ----
        float t0 = -INFINITY, t1 = -INFINITY, t2 = -INFINITY, t3 = -INFINITY;
        {
            const bool ulo = (kvsa + 31 - qw <= -MAXREL);
            const bool uhi = (kvsa - (qw + 31) >= MAXREL);
            if (ulo || uhi) {
                const float bc = ulo ? TbLo : TbHi;
                #pragma unroll
                for (int m = 0; m < 4; ++m) {
                    float s0 = sa[4 * m + 0] + bc;  sa[4 * m + 0] = s0;  t0 = fmaxf(t0, s0);
                    float s1 = sa[4 * m + 1] + bc;  sa[4 * m + 1] = s1;  t1 = fmaxf(t1, s1);
                    float s2 = sa[4 * m + 2] + bc;  sa[4 * m + 2] = s2;  t2 = fmaxf(t2, s2);
                    float s3 = sa[4 * m + 3] + bc;  sa[4 * m + 3] = s3;  t3 = fmaxf(t3, s3);
                }
            } else {
                #pragma unroll
                for (int m = 0; m < 4; ++m) {
                    const int jb = jb0 + kv0a + m * 8;
                    float s0 = sa[4 * m + 0] + Tw[jb + 0];  sa[4 * m + 0] = s0;  t0 = fmaxf(t0, s0);
                    float s1 = sa[4 * m + 1] + Tw[jb + 1];  sa[4 * m + 1] = s1;  t1 = fmaxf(t1, s1);
                    float s2 = sa[4 * m + 2] + Tw[jb + 2];  sa[4 * m + 2] = s2;  t2 = fmaxf(t2, s2);
                    float s3 = sa[4 * m + 3] + Tw[jb + 3];  sa[4 * m + 3] = s3;  t3 = fmaxf(t3, s3);
                }
            }
            const bool ulo1 = (kvsb + 31 - qw <= -MAXREL);
            const bool uhi1 = (kvsb - (qw + 31) >= MAXREL);
            if (ulo1 || uhi1) {
                const float bc = ulo1 ? TbLo : TbHi;
                #pragma unroll
                for (int m = 0; m < 4; ++m) {
                    float s0 = sb[4 * m + 0] + bc;  sb[4 * m + 0] = s0;  t0 = fmaxf(t0, s0);
                    float s1 = sb[4 * m + 1] + bc;  sb[4 * m + 1] = s1;  t1 = fmaxf(t1, s1);
                    float s2 = sb[4 * m + 2] + bc;  sb[4 * m + 2] = s2;  t2 = fmaxf(t2, s2);
                    float s3 = sb[4 * m + 3] + bc;  sb[4 * m + 3] = s3;  t3 = fmaxf(t3, s3);
                }
            } else {
                #pragma unroll
                for (int m = 0; m < 4; ++m) {
                    const int jb = jb0 + kv0b + m * 8;
                    float s0 = sb[4 * m + 0] + Tw[jb + 0];  sb[4 * m + 0] = s0;  t0 = fmaxf(t0, s0);
                    float s1 = sb[4 * m + 1] + Tw[jb + 1];  sb[4 * m + 1] = s1;  t1 = fmaxf(t1, s1);
                    float s2 = sb[4 * m + 2] + Tw[jb + 2];  sb[4 * m + 2] = s2;  t2 = fmaxf(t2, s2);
                    float s3 = sb[4 * m + 3] + Tw[jb + 3];  sb[4 * m + 3] = s3;  t3 = fmaxf(t3, s3);
                }
            }
        }
        float tmaxl = fmaxf(fmaxf(t0, t1), fmaxf(t2, t3));
        const float tmax = fmaxf(tmaxl, __shfl_xor(tmaxl, 32));   // row = lanes q, q+32

        // ---- single defer-max decision per pair (check BEFORE exp; exp exactly once) ----
        if (!__all(tmax <= m_s + 8.0f)) {
            const float mnew = fmaxf(m_s, tmax);
            const float fac = ex2(m_s - mnew);
            lsum *= fac;
            ca0 *= fac;
            ca1 *= fac;
            m_s = mnew;
        }

        float ptile = 0.f;
        unsigned int pka[8], pkb[8];
        #pragma unroll
        for (int m = 0; m < 4; ++m) {
            float a0 = ex2(sa[4 * m + 0] - m_s), a1 = ex2(sa[4 * m + 1] - m_s);
            float a2 = ex2(sa[4 * m + 2] - m_s), a3 = ex2(sa[4 * m + 3] - m_s);
            float b0 = ex2(sb[4 * m + 0] - m_s), b1 = ex2(sb[4 * m + 1] - m_s);
            float b2 = ex2(sb[4 * m + 2] - m_s), b3 = ex2(sb[4 * m + 3] - m_s);
            ptile += ((a0 + a1) + (a2 + a3)) + ((b0 + b1) + (b2 + b3));
            asm("v_cvt_pk_bf16_f32 %0, %1, %2" : "=v"(pka[2 * m])     : "v"(a0), "v"(a1));
            asm("v_cvt_pk_bf16_f32 %0, %1, %2" : "=v"(pka[2 * m + 1]) : "v"(a2), "v"(a3));
            asm("v_cvt_pk_bf16_f32 %0, %1, %2" : "=v"(pkb[2 * m])     : "v"(b0), "v"(b1));
            asm("v_cvt_pk_bf16_f32 %0, %1, %2" : "=v"(pkb[2 * m + 1]) : "v"(b2), "v"(b3));
        }
        lsum += ptile;

        // ---- P B-frags via permlane32_swap (kv-local [0,32)) ----
        bf8 pf0a, pf1a, pf0b, pf1b;
        {
            unsigned c0 = pka[0], c2 = pka[2], c1 = pka[1], c3 = pka[3];
            asm("v_permlane32_swap_b32 %0, %1" : "+v"(c0), "+v"(c2));
            asm("v_permlane32_swap_b32 %0, %1" : "+v"(c1), "+v"(c3));
            pf0a = mkbf8(c0, c1, c2, c3);
        }
        {
            unsigned c0 = pka[4], c2 = pka[6], c1 = pka[5], c3 = pka[7];
            asm("v_permlane32_swap_b32 %0, %1" : "+v"(c0), "+v"(c2));
            asm("v_permlane32_swap_b32 %0, %1" : "+v"(c1), "+v"(c3));
            pf1a = mkbf8(c0, c1, c2, c3);
        }
        {
            unsigned c0 = pkb[0], c2 = pkb[2], c1 = pkb[1], c3 = pkb[3];
            asm("v_permlane32_swap_b32 %0, %1" : "+v"(c0), "+v"(c2));
            asm("v_permlane32_swap_b32 %0, %1" : "+v"(c1), "+v"(c3));
            pf0b = mkbf8(c0, c1, c2, c3);
        }
        {
            unsigned c0 = pkb[4], c2 = pkb[6], c1 = pkb[5], c3 = pkb[7];
            asm("v_permlane32_swap_b32 %0, %1" : "+v"(c0), "+v"(c2));
            asm("v_permlane32_swap_b32 %0, %1" : "+v"(c1), "+v"(c3));
            pf1b = mkbf8(c0, c1, c2, c3);
        }

        // ---- PV both tiles (8 independent MFMA32) ----
        __builtin_amdgcn_s_setprio(1);
        #pragma unroll
        for (int s = 0; s < 2; ++s) {
            const int slot = ((4 * kvh + 2 * s + hi) ^ xq) * 8;
            bf8 va0 = *(const bf8*)&Vta[q * 64 + slot];
            bf8 va1 = *(const bf8*)&Vta[(q + 32) * 64 + slot];
            bf8 vb0_ = *(const bf8*)&Vtb[q * 64 + slot];
            bf8 vb1_ = *(const bf8*)&Vtb[(q + 32) * 64 + slot];
            bf8 pfa = (s == 0) ? pf0a : pf1a;
            bf8 pfb = (s == 0) ? pf0b : pf1b;
            ca0 = MFMA32(va0, pfa, ca0);
            ca1 = MFMA32(va1, pfa, ca1);
            ca0 = MFMA32(vb0_, pfb, ca0);
            ca1 = MFMA32(vb1_, pfb, ca1);
        }
        __builtin_amdgcn_s_setprio(0);

        // ---- sync + stage pair p+2 into the just-read bufset ----
        if (p < 15) {
            __builtin_amdgcn_s_barrier();            // all waves done reading bufset bs
            if (p < 14) {
                stage(2 * (p + 2), bs);
                stage(2 * (p + 2) + 1, bs + 1);
                asm volatile("s_waitcnt vmcnt(4)" ::: "memory");   // pair p+1 ready
            } else {
                asm volatile("s_waitcnt vmcnt(0)" ::: "memory");   // pair 15 ready
            }
            __builtin_amdgcn_s_barrier();
            __builtin_amdgcn_sched_barrier(0);
        }
    }

    // ---- reduce l across the lane pair (q, q+32) ----
    lsum += __shfl_xor(lsum, 32);

    // ---- pair-merge through LDS (overlay on KV ring) ----
    __syncthreads();                          // all waves done with the ring
    float* mg = (float*)&KV[0][0];            // [4 pairs][34][64] floats = 34.8 KB
    if (kvh == 1) {                           // writers: upper-half waves
        const int base = g * 34 * 64;
        #pragma unroll
        for (int j = 0; j < 16; ++j) mg[base + j * 64 + lane] = ca0[j];
        #pragma unroll
        for (int j = 0; j < 16; ++j) mg[base + (16 + j) * 64 + lane] = ca1[j];
        mg[base + 32 * 64 + lane] = m_s;
        mg[base + 33 * 64 + lane] = lsum;
    }
    __syncthreads();
    if (kvh == 0) {                           // readers: merge + epilogue
        const int base = g * 34 * 64;
        const float pm = mg[base + 32 * 64 + lane];
        const float pl = mg[base + 33 * 64 + lane];
        const float mm = fmaxf(m_s, pm);
        const float fa = ex2(m_s - mm);
        const float fb = ex2(pm - mm);
        const float lm = lsum * fa + pl * fb;
        const float inv = 1.0f / lm;
        unsigned short* cg = &ctx[(size_t)(b * S_ + myq) * HID_ + h * HD_];
        #pragma unroll
        for (int m = 0; m < 4; ++m) {
            ushort4 o0;
            o0.x = f2bf((ca0[4 * m + 0] * fa + mg[base + (4 * m + 0) * 64 + lane] * fb) * inv);
            o0.y = f2bf((ca0[4 * m + 1] * fa + mg[base + (4 * m + 1) * 64 + lane] * fb) * inv);
            o0.z = f2bf((ca0[4 * m + 2] * fa + mg[base + (4 * m + 2) * 64 + lane] * fb) * inv);
            o0.w = f2bf((ca0[4 * m + 3] * fa + mg[base + (4 * m + 3) * 64 + lane] * fb) * inv);
            *(ushort4*)&cg[m * 8 + hi * 4] = o0;
            ushort4 o1;
            o1.x = f2bf((ca1[4 * m + 0] * fa + mg[base + (16 + 4 * m + 0) * 64 + lane] * fb) * inv);
            o1.y = f2bf((ca1[4 * m + 1] * fa + mg[base + (16 + 4 * m + 1) * 64 + lane] * fb) * inv);
            o1.z = f2bf((ca1[4 * m + 2] * fa + mg[base + (16 + 4 * m + 2) * 64 + lane] * fb) * inv);
            o1.w = f2bf((ca1[4 * m + 3] * fa + mg[base + (16 + 4 * m + 3) * 64 + lane] * fb) * inv);
            *(ushort4*)&cg[32 + m * 8 + hi * 4] = o1;
        }
    }
}

// ---------------- launcher ----------------
extern "C" void kernel_launch(void* const* d_in, const int* in_sizes, int n_in,
                              void* d_out, int out_size, void* d_ws, size_t ws_size,
                              hipStream_t stream) {
    const float* hs  = (const float*)d_in[0];
    const float* msk = (const float*)d_in[1];
    const float* Wq  = (const float*)d_in[2];
    const float* bq  = (const float*)d_in[3];
    const float* Wk  = (const float*)d_in[4];
    const float* bk  = (const float*)d_in[5];
    const float* Wv  = (const float*)d_in[6];
    const float* bv  = (const float*)d_in[7];
    const float* Wo  = (const float*)d_in[8];
    const float* bo  = (const float*)d_in[9];
    const float* rel = (const float*)d_in[10];
    float* out = (float*)d_out;

    char* ws = (char*)d_ws;
    unsigned short* hsb = (unsigned short*)ws; ws += (size_t)M_ * HID_ * 2;
    unsigned short* Wqt = (unsigned short*)ws; ws += (size_t)HID_ * HID_ * 2;
    unsigned short* Wkt = (unsigned short*)ws; ws += (size_t)HID_ * HID_ * 2;
    unsigned short* Wvt = (unsigned short*)ws; ws += (size_t)HID_ * HID_ * 2;
    unsigned short* Wot = (unsigned short*)ws; ws += (size_t)HID_ * HID_ * 2;
    unsigned short* Qb  = (unsigned short*)ws; ws += (size_t)M_ * HID_ * 2;
    unsigned short* Kb  = (unsigned short*)ws; ws += (size_t)M_ * HID_ * 2;
    unsigned short* Vtb = (unsigned short*)ws; ws += (size_t)M_ * HID_ * 2;
    unsigned short* ctxb= (unsigned short*)ws; ws += (size_t)M_ * HID_ * 2;
    unsigned* maskbits  = (unsigned*)ws;       ws += (size_t)B_ * 64 * 4;

    k_cast_hs<<<(M_ * HID_ / 4 + 255) / 256, 256, 0, stream>>>(
        hs, hsb, M_ * HID_ / 4, msk, maskbits);
    k_transpose_w4<<<dim3(16, 16, 4), 256, 0, stream>>>(Wq, Wk, Wv, Wo, Wqt, Wkt, Wvt, Wot);
    k_gemm_qkv<<<dim3(64, 12), 256, 0, stream>>>(
        hsb, Wqt, Wkt, Wvt, bq, bk, bv, Qb, Kb, Vtb);
    k_flash<<<512, 512, 0, stream>>>(Qb, Kb, Vtb, rel, maskbits, ctxb);
    k_gemm_out<<<dim3(64, 4), 512, 0, stream>>>(ctxb, Wot, bo, out);
}

// Round 16
// 105.222 us; speedup vs baseline: 1.0283x; 1.0283x over previous
//
#include <hip/hip_runtime.h>
#include <hip/hip_bf16.h>

#define B_    4
#define S_    2048
#define HID_  512
#define NH_   8
#define HD_   64
#define MAXREL 512
#define M_    (B_ * S_)   // 8192 tokens

#define LOG2E 1.44269504f
#define SCALE_Q (0.125f * LOG2E)   // folded into Q at projection time

typedef __attribute__((ext_vector_type(8))) short bf8;            // 8 bf16 (MFMA A/B frag)
typedef __attribute__((ext_vector_type(4))) float f4;             // 16x16 C/D frag
typedef __attribute__((ext_vector_type(16))) float f16f;          // 32x32 C/D frag

static __device__ __forceinline__ unsigned short f2bf(float f) {
    union { float f; unsigned int u; } v; v.f = f;
    unsigned int u = v.u;
    unsigned int r = (u + 0x7FFFu + ((u >> 16) & 1u)) >> 16;   // round-nearest-even
    return (unsigned short)r;
}

static __device__ __forceinline__ float ex2(float x) {   // raw v_exp_f32 (base-2)
    float r; asm("v_exp_f32 %0, %1" : "=v"(r) : "v"(x)); return r;
}

// async global->LDS, 16B per lane; dest = wave-uniform base + lane*16 (linear)
static __device__ __forceinline__ void gload16(const void* g, void* l) {
    __builtin_amdgcn_global_load_lds(
        (const __attribute__((address_space(1))) unsigned int*)g,
        (__attribute__((address_space(3))) unsigned int*)l, 16, 0, 0);
}

static __device__ __forceinline__ bf8 mkbf8(unsigned a, unsigned b, unsigned c, unsigned d) {
    uint4 u = make_uint4(a, b, c, d);
    return *(bf8*)&u;
}

#define MFMA16(a, b, c) __builtin_amdgcn_mfma_f32_16x16x32_bf16((a), (b), (c), 0, 0, 0)
#define MFMA32(a, b, c) __builtin_amdgcn_mfma_f32_32x32x16_bf16((a), (b), (c), 0, 0, 0)

// ---------------- cast hidden_states fp32 -> bf16 + mask bit-pack (block 0) ----------------
__global__ void k_cast_hs(const float* __restrict__ src, unsigned short* __restrict__ dst, int n4,
                          const float* __restrict__ mask, unsigned* __restrict__ maskbits) {
    int i = blockIdx.x * blockDim.x + threadIdx.x;
    if (i < n4) {
        float4 v = ((const float4*)src)[i];
        ushort4 o;
        o.x = f2bf(v.x); o.y = f2bf(v.y); o.z = f2bf(v.z); o.w = f2bf(v.w);
        ((ushort4*)dst)[i] = o;
    }
    if (blockIdx.x == 0 && threadIdx.x < 256) {
        const int t = threadIdx.x;
        const int b = t >> 6, wd = t & 63;
        unsigned bits = 0;
        #pragma unroll
        for (int j = 0; j < 32; ++j)
            bits |= (mask[b * S_ + wd * 32 + j] > 0.5f ? 1u : 0u) << j;
        maskbits[t] = bits;
    }
}

// ---------------- transpose + cast 4 weights (LDS 32x32 tiles) ----------------
__global__ void k_transpose_w4(const float* __restrict__ W0, const float* __restrict__ W1,
                               const float* __restrict__ W2, const float* __restrict__ W3,
                               unsigned short* __restrict__ T0, unsigned short* __restrict__ T1,
                               unsigned short* __restrict__ T2, unsigned short* __restrict__ T3) {
    __shared__ float tile[32][33];
    const int z = blockIdx.z;
    const float* W = (z == 0) ? W0 : (z == 1) ? W1 : (z == 2) ? W2 : W3;
    unsigned short* T = (z == 0) ? T0 : (z == 1) ? T1 : (z == 2) ? T2 : T3;
    const int tx = threadIdx.x & 31, ty = threadIdx.x >> 5;   // 256 thr
    const int n0 = blockIdx.x * 32, k0 = blockIdx.y * 32;
    #pragma unroll
    for (int i = 0; i < 4; ++i)
        tile[ty + i * 8][tx] = W[(size_t)(k0 + ty + i * 8) * HID_ + n0 + tx];
    __syncthreads();
    #pragma unroll
    for (int i = 0; i < 4; ++i)
        T[(size_t)(n0 + ty + i * 8) * HID_ + k0 + tx] = f2bf(tile[tx][ty + i * 8]);
}

// ---------------- fused QKV GEMM: 128x128 tile, dbuf LDS via global_load_lds ----------------
__global__ __launch_bounds__(256, 3) void k_gemm_qkv(
    const unsigned short* __restrict__ Abf,
    const unsigned short* __restrict__ Wqt, const unsigned short* __restrict__ Wkt,
    const unsigned short* __restrict__ Wvt,
    const float* __restrict__ bq, const float* __restrict__ bk, const float* __restrict__ bv,
    unsigned short* __restrict__ Q, unsigned short* __restrict__ K, unsigned short* __restrict__ Vt)
{
    __shared__ unsigned short Al[2][128 * 32];
    __shared__ unsigned short Bl[2][128 * 32];

    const int t = threadIdx.x;
    const int lane = t & 63, w = t >> 6;
    const int lr = lane & 15, lg = lane >> 4;
    const int wr = w >> 1, wc = w & 1;

    const int m0 = blockIdx.x * 128;
    const int ng = blockIdx.y * 128;
    const int z = ng >> 9;
    const int n0 = ng & 511;
    const unsigned short* Wt = (z == 0) ? Wqt : ((z == 1) ? Wkt : Wvt);
    const float* bias = (z == 0) ? bq : ((z == 1) ? bk : bv);
    const float osc = (z == 0) ? SCALE_Q : 1.0f;

    const int srow = t >> 2;
    const int sc = (((t & 3) ^ ((srow >> 1) & 3))) * 8;     // swizzled source col
    const unsigned short* Ag0 = &Abf[(size_t)(m0 + srow) * HID_ + sc];
    const unsigned short* Ag1 = &Abf[(size_t)(m0 + 64 + srow) * HID_ + sc];
    const unsigned short* Bg0 = &Wt[(size_t)(n0 + srow) * HID_ + sc];
    const unsigned short* Bg1 = &Wt[(size_t)(n0 + 64 + srow) * HID_ + sc];
    char* dA0 = (char*)&Al[0][0] + w * 1024;
    char* dB0 = (char*)&Bl[0][0] + w * 1024;

    const int fx = (lr >> 1) & 3;
    int aoff[4], boff[4];
    #pragma unroll
    for (int i = 0; i < 4; ++i) {
        aoff[i] = (wr * 64 + i * 16 + lr) * 32 + ((lg ^ fx) * 8);
        boff[i] = (wc * 64 + i * 16 + lr) * 32 + ((lg ^ fx) * 8);
    }

    gload16(Ag0, dA0);
    gload16(Ag1, dA0 + 4096);
    gload16(Bg0, dB0);
    gload16(Bg1, dB0 + 4096);
    __syncthreads();

    f4 acc[4][4] = {};
    for (int kt = 0; kt < 16; ++kt) {
        const int cur = kt & 1;
        if (kt < 15) {
            const int ko = (kt + 1) * 32;
            const int bo = (cur ^ 1) * 8192;
            gload16(Ag0 + ko, dA0 + bo);
            gload16(Ag1 + ko, dA0 + bo + 4096);
            gload16(Bg0 + ko, dB0 + bo);
            gload16(Bg1 + ko, dB0 + bo + 4096);
        }
        bf8 af[4], bf_[4];
        #pragma unroll
        for (int i = 0; i < 4; ++i) {
            af[i]  = *(const bf8*)&Al[cur][aoff[i]];
            bf_[i] = *(const bf8*)&Bl[cur][boff[i]];
        }
        #pragma unroll
        for (int mi = 0; mi < 4; ++mi)
            #pragma unroll
            for (int ni = 0; ni < 4; ++ni)
                acc[mi][ni] = MFMA16(af[mi], bf_[ni], acc[mi][ni]);
        __syncthreads();
    }

    #pragma unroll
    for (int mi = 0; mi < 4; ++mi)
    #pragma unroll
    for (int ni = 0; ni < 4; ++ni) {
        const int col = n0 + wc * 64 + ni * 16 + lr;
        const int h = col >> 6, d = col & 63;
        const float bs = bias[col];
        const int row0 = m0 + wr * 64 + mi * 16 + lg * 4;
        const int b = row0 >> 11, s0 = row0 & 2047;
        if (z == 2) {
            ushort4 o;
            o.x = f2bf(acc[mi][ni][0] + bs);
            o.y = f2bf(acc[mi][ni][1] + bs);
            o.z = f2bf(acc[mi][ni][2] + bs);
            o.w = f2bf(acc[mi][ni][3] + bs);
            *(ushort4*)&Vt[(((size_t)(b * NH_ + h)) * HD_ + d) * S_ + s0] = o;
        } else {
            unsigned short* dst = (z == 0) ? Q : K;
            #pragma unroll
            for (int r = 0; r < 4; ++r) {
                float v = (acc[mi][ni][r] + bs) * osc;
                dst[(((size_t)(b * NH_ + h)) * S_ + s0 + r) * HD_ + d] = f2bf(v);
            }
        }
    }
}

// ---------------- output projection GEMM: 128x128 tile, 512 threads ----------------
__global__ __launch_bounds__(512) void k_gemm_out(
    const unsigned short* __restrict__ Abf,
    const unsigned short* __restrict__ Wot,
    const float* __restrict__ bo,
    float* __restrict__ out)
{
    __shared__ unsigned short Al[2][128 * 32];
    __shared__ unsigned short Bl[2][128 * 32];

    const int t = threadIdx.x;
    const int lane = t & 63, w = t >> 6;          // 8 waves, 2x4
    const int lr = lane & 15, lg = lane >> 4;
    const int wr = w >> 2, wc = w & 3;

    const int m0 = blockIdx.x * 128;
    const int n0 = blockIdx.y * 128;

    const int srow = t >> 2;
    const int sc = (((t & 3) ^ ((srow >> 1) & 3))) * 8;
    const unsigned short* Ag = &Abf[(size_t)(m0 + srow) * HID_ + sc];
    const unsigned short* Bg = &Wot[(size_t)(n0 + srow) * HID_ + sc];
    char* dA = (char*)&Al[0][0] + w * 1024;
    char* dB = (char*)&Bl[0][0] + w * 1024;

    const int fx = (lr >> 1) & 3;
    int aoff[4], boff[2];
    #pragma unroll
    for (int i = 0; i < 4; ++i)
        aoff[i] = (wr * 64 + i * 16 + lr) * 32 + ((lg ^ fx) * 8);
    #pragma unroll
    for (int i = 0; i < 2; ++i)
        boff[i] = (wc * 32 + i * 16 + lr) * 32 + ((lg ^ fx) * 8);

    gload16(Ag, dA);
    gload16(Bg, dB);
    __syncthreads();

    f4 acc[4][2] = {};
    for (int kt = 0; kt < 16; ++kt) {
        const int cur = kt & 1;
        if (kt < 15) {
            const int ko = (kt + 1) * 32;
            const int bo_ = (cur ^ 1) * 8192;
            gload16(Ag + ko, dA + bo_);
            gload16(Bg + ko, dB + bo_);
        }
        bf8 af[4], bf_[2];
        #pragma unroll
        for (int i = 0; i < 4; ++i) af[i] = *(const bf8*)&Al[cur][aoff[i]];
        #pragma unroll
        for (int i = 0; i < 2; ++i) bf_[i] = *(const bf8*)&Bl[cur][boff[i]];
        #pragma unroll
        for (int mi = 0; mi < 4; ++mi)
            #pragma unroll
            for (int ni = 0; ni < 2; ++ni)
                acc[mi][ni] = MFMA16(af[mi], bf_[ni], acc[mi][ni]);
        __syncthreads();
    }

    #pragma unroll
    for (int mi = 0; mi < 4; ++mi)
    #pragma unroll
    for (int ni = 0; ni < 2; ++ni) {
        const int col = n0 + wc * 32 + ni * 16 + lr;
        const float bs = bo[col];
        const int row0 = m0 + wr * 64 + mi * 16 + lg * 4;
        #pragma unroll
        for (int r = 0; r < 4; ++r)
            out[(size_t)(row0 + r) * HID_ + col] = acc[mi][ni][r] + bs;
    }
}

// ---------------- flash attention: 8 waves = 4 q-groups x 2 kv-halves, mfma 32x32x16.
//   R13 structure + mask as register bitmask (scalar fast-path skip), no maskc LDS. ----------------
__global__ __launch_bounds__(512, 4) void k_flash(
    const unsigned short* __restrict__ Q, const unsigned short* __restrict__ K,
    const unsigned short* __restrict__ Vt,
    const float* __restrict__ rel_table, const unsigned* __restrict__ maskbits,
    unsigned short* __restrict__ ctx)
{
    __shared__ unsigned short KV[3][8192];   // per buf: [0,4096) ushorts K, [4096,8192) V
    __shared__ float Tw[1216];               // bias window, rel in [-605,605], pre-clipped, *log2e

    const int t = threadIdx.x;
    const int lane = t & 63, w = t >> 6;     // 8 waves
    const int q = lane & 31, hi = lane >> 5;
    const int g = w & 3, kvh = w >> 2;       // q-group, kv-half

    // bijective XCD swizzle: each XCD owns 4 complete (b,h) pairs
    const int flat = blockIdx.x;             // 0..511
    const int idx = flat >> 3;
    const int bh = (flat & 7) * 4 + (idx >> 4);
    const int qb = idx & 15;
    const int b = bh >> 3, h = bh & 7;
    const int q0 = qb * 128;

    // mask words for this wave's kv windows: lane ti (<32) holds word for tile ti
    unsigned mword = 0xFFFFFFFFu;
    if (lane < 32) mword = maskbits[b * 64 + 2 * lane + kvh];

    for (int i = t; i < 1216; i += 512) {
        int r = i - 606;
        r = r < -MAXREL ? -MAXREL : (r > MAXREL ? MAXREL : r);
        Tw[i] = rel_table[(r + MAXREL) * NH_ + h] * LOG2E;
    }
    const float TbLo = rel_table[h] * LOG2E;                    // rel = -512
    const float TbHi = rel_table[2 * MAXREL * NH_ + h] * LOG2E; // rel = +512

    const unsigned short* Kb = K + (size_t)bh * S_ * HD_;
    const unsigned short* Vb = Vt + (size_t)bh * HD_ * S_;

    const int myq = q0 + g * 32 + q;
    const int qw = q0 + g * 32;
    bf8 qf[4];   // B-frag: col=q, k(d)=16s+8hi+j
    #pragma unroll
    for (int s = 0; s < 4; ++s)
        qf[s] = *(const bf8*)&Q[((size_t)bh * S_ + myq) * HD_ + s * 16 + hi * 8];

    // staging (512 thr): thread t -> row t>>3 (0..63), slot t&7; source col pre-swizzled
    const int srow = t >> 3, sslot = t & 7;
    const int sxor = (sslot ^ (srow & 7)) * 8;
    const size_t kb0 = (size_t)srow * HD_ + sxor;
    const size_t vb0 = (size_t)srow * S_ + sxor;
    const int woff = w * 1024;               // wave's linear 1KB chunk (8 rows x 128B)

    auto stage = [&](int kvt, int buf) {
        char* base = (char*)&KV[buf][0];
        gload16(&Kb[kb0 + (size_t)kvt * 64 * HD_], base + woff);
        gload16(&Vb[vb0 + (size_t)kvt * 64], base + 8192 + woff);
    };

    f16f ca0 = {}, ca1 = {};       // ctx^T partial: col=q, d = {0,32} + (reg&3)+8*(reg>>2)+4hi
    float m_s = -INFINITY, lsum = 0.f;

    // prologue: 2 tiles in flight (2 loads/wave each)
    stage(0, 0);
    stage(1, 1);
    asm volatile("s_waitcnt lgkmcnt(0)" ::: "memory");   // Tw ds_writes drained
    asm volatile("s_waitcnt vmcnt(2)" ::: "memory");     // buf0 ready
    __builtin_amdgcn_s_barrier();
    __builtin_amdgcn_sched_barrier(0);

    const int xq = q & 7;
    // Tw index: 606 + key - myq; key = kv0 + 32*kvh + 8m + 4hi + r
    const int jb0 = 606 + 32 * kvh + 4 * hi - q0 - g * 32 - q;   // + kv0 + 8m + r
    for (int ti = 0; ti < 32; ++ti) {
        const int kv0 = ti * 64;
        const int cur = ti % 3;
        const int kvs = kv0 + 32 * kvh;      // this wave's 32-key window

        if (ti < 30) stage(ti + 2, (ti + 2) % 3);

        const unsigned short* Kt  = &KV[cur][0];
        const unsigned short* Vtl = &KV[cur][4096];

        // ---- QK^T (swapped): C[key_local][q], this wave's 32 keys ----
        f16f sa = {};
        __builtin_amdgcn_s_setprio(1);
        #pragma unroll
        for (int s = 0; s < 4; ++s) {
            bf8 kf = *(const bf8*)&Kt[(32 * kvh + q) * 64 + (((2 * s + hi) ^ xq) * 8)];
            sa = MFMA32(kf, qf[s], sa);
        }
        __builtin_amdgcn_s_setprio(0);

        // ---- mask (rare slow path; scalar-uniform skip when all-attend) ----
        const unsigned mws = __builtin_amdgcn_readlane(mword, ti);
        if (mws != 0xFFFFFFFFu) {
            #pragma unroll
            for (int m = 0; m < 4; ++m) {
                const unsigned tb = mws >> (8 * m + 4 * hi);
                #pragma unroll
                for (int r = 0; r < 4; ++r)
                    sa[4 * m + r] += ((tb >> r) & 1) ? 0.f : -3.0e38f;
            }
        }

        // ---- bias + row max (4 parallel max accumulators) ----
        float t0 = -INFINITY, t1 = -INFINITY, t2 = -INFINITY, t3 = -INFINITY;
        {
            const bool ulo = (kvs + 31 - qw <= -MAXREL);
            const bool uhi = (kvs - (qw + 31) >= MAXREL);
            if (ulo || uhi) {
                const float bc = ulo ? TbLo : TbHi;
                #pragma unroll
                for (int m = 0; m < 4; ++m) {
                    float s0 = sa[4 * m + 0] + bc;  sa[4 * m + 0] = s0;  t0 = fmaxf(t0, s0);
                    float s1 = sa[4 * m + 1] + bc;  sa[4 * m + 1] = s1;  t1 = fmaxf(t1, s1);
                    float s2 = sa[4 * m + 2] + bc;  sa[4 * m + 2] = s2;  t2 = fmaxf(t2, s2);
                    float s3 = sa[4 * m + 3] + bc;  sa[4 * m + 3] = s3;  t3 = fmaxf(t3, s3);
                }
            } else {
                #pragma unroll
                for (int m = 0; m < 4; ++m) {
                    const int jb = jb0 + kv0 + m * 8;
                    float s0 = sa[4 * m + 0] + Tw[jb + 0];  sa[4 * m + 0] = s0;  t0 = fmaxf(t0, s0);
                    float s1 = sa[4 * m + 1] + Tw[jb + 1];  sa[4 * m + 1] = s1;  t1 = fmaxf(t1, s1);
                    float s2 = sa[4 * m + 2] + Tw[jb + 2];  sa[4 * m + 2] = s2;  t2 = fmaxf(t2, s2);
                    float s3 = sa[4 * m + 3] + Tw[jb + 3];  sa[4 * m + 3] = s3;  t3 = fmaxf(t3, s3);
                }
            }
        }
        float tmaxl = fmaxf(fmaxf(t0, t1), fmaxf(t2, t3));
        const float tmax = fmaxf(tmaxl, __shfl_xor(tmaxl, 32));   // row = lanes q, q+32

        // ---- speculative exp with current m_s (defer-max common case) ----
        float ptile = 0.f;
        unsigned int pk[8];
        #pragma unroll
        for (int m = 0; m < 4; ++m) {
            float a0 = ex2(sa[4 * m + 0] - m_s), a1 = ex2(sa[4 * m + 1] - m_s);
            float a2 = ex2(sa[4 * m + 2] - m_s), a3 = ex2(sa[4 * m + 3] - m_s);
            ptile += (a0 + a1) + (a2 + a3);
            asm("v_cvt_pk_bf16_f32 %0, %1, %2" : "=v"(pk[2 * m])     : "v"(a0), "v"(a1));
            asm("v_cvt_pk_bf16_f32 %0, %1, %2" : "=v"(pk[2 * m + 1]) : "v"(a2), "v"(a3));
        }
        if (!__all(tmax <= m_s + 8.0f)) {     // rare: rescale + recompute
            const float mnew = fmaxf(m_s, tmax);
            const float fac = ex2(m_s - mnew);
            lsum *= fac;
            ca0 *= fac;
            ca1 *= fac;
            ptile = 0.f;
            #pragma unroll
            for (int m = 0; m < 4; ++m) {
                float a0 = ex2(sa[4 * m + 0] - mnew), a1 = ex2(sa[4 * m + 1] - mnew);
                float a2 = ex2(sa[4 * m + 2] - mnew), a3 = ex2(sa[4 * m + 3] - mnew);
                ptile += (a0 + a1) + (a2 + a3);
                asm("v_cvt_pk_bf16_f32 %0, %1, %2" : "=v"(pk[2 * m])     : "v"(a0), "v"(a1));
                asm("v_cvt_pk_bf16_f32 %0, %1, %2" : "=v"(pk[2 * m + 1]) : "v"(a2), "v"(a3));
            }
            m_s = mnew;
        }
        lsum += ptile;

        // ---- P B-frags via permlane32_swap (kv-local [0,32)) ----
        bf8 pf0, pf1;
        {
            unsigned c0 = pk[0], c2 = pk[2], c1 = pk[1], c3 = pk[3];
            asm("v_permlane32_swap_b32 %0, %1" : "+v"(c0), "+v"(c2));
            asm("v_permlane32_swap_b32 %0, %1" : "+v"(c1), "+v"(c3));
            pf0 = mkbf8(c0, c1, c2, c3);
        }
        {
            unsigned c0 = pk[4], c2 = pk[6], c1 = pk[5], c3 = pk[7];
            asm("v_permlane32_swap_b32 %0, %1" : "+v"(c0), "+v"(c2));
            asm("v_permlane32_swap_b32 %0, %1" : "+v"(c1), "+v"(c3));
            pf1 = mkbf8(c0, c1, c2, c3);
        }

        // ---- PV (swapped): C[d][q] += mfma32(V^T frag, P frag), kv = this half ----
        __builtin_amdgcn_s_setprio(1);
        #pragma unroll
        for (int s = 0; s < 2; ++s) {
            const int slot = ((4 * kvh + 2 * s + hi) ^ xq) * 8;
            bf8 v0 = *(const bf8*)&Vtl[q * 64 + slot];
            bf8 v1 = *(const bf8*)&Vtl[(q + 32) * 64 + slot];
            bf8 pf = (s == 0) ? pf0 : pf1;
            ca0 = MFMA32(v0, pf, ca0);
            ca1 = MFMA32(v1, pf, ca1);
        }
        __builtin_amdgcn_s_setprio(0);

        // ---- counted-vmcnt barrier ----
        if (ti < 31) {
            if (ti < 30) asm volatile("s_waitcnt vmcnt(2)" ::: "memory");
            else         asm volatile("s_waitcnt vmcnt(0)" ::: "memory");
            __builtin_amdgcn_s_barrier();
            __builtin_amdgcn_sched_barrier(0);
        }
    }

    // ---- reduce l across the lane pair (q, q+32) ----
    lsum += __shfl_xor(lsum, 32);

    // ---- pair-merge through LDS (overlay on KV ring) ----
    __syncthreads();                          // all waves done with the ring
    float* mg = (float*)&KV[0][0];            // [4 pairs][34][64] floats = 34.8 KB
    if (kvh == 1) {                           // writers: upper-half waves
        const int base = g * 34 * 64;
        #pragma unroll
        for (int j = 0; j < 16; ++j) mg[base + j * 64 + lane] = ca0[j];
        #pragma unroll
        for (int j = 0; j < 16; ++j) mg[base + (16 + j) * 64 + lane] = ca1[j];
        mg[base + 32 * 64 + lane] = m_s;
        mg[base + 33 * 64 + lane] = lsum;
    }
    __syncthreads();
    if (kvh == 0) {                           // readers: merge + epilogue
        const int base = g * 34 * 64;
        const float pm = mg[base + 32 * 64 + lane];
        const float pl = mg[base + 33 * 64 + lane];
        const float mm = fmaxf(m_s, pm);
        const float fa = ex2(m_s - mm);
        const float fb = ex2(pm - mm);
        const float lm = lsum * fa + pl * fb;
        const float inv = 1.0f / lm;
        unsigned short* cg = &ctx[(size_t)(b * S_ + myq) * HID_ + h * HD_];
        #pragma unroll
        for (int m = 0; m < 4; ++m) {
            ushort4 o0;
            o0.x = f2bf((ca0[4 * m + 0] * fa + mg[base + (4 * m + 0) * 64 + lane] * fb) * inv);
            o0.y = f2bf((ca0[4 * m + 1] * fa + mg[base + (4 * m + 1) * 64 + lane] * fb) * inv);
            o0.z = f2bf((ca0[4 * m + 2] * fa + mg[base + (4 * m + 2) * 64 + lane] * fb) * inv);
            o0.w = f2bf((ca0[4 * m + 3] * fa + mg[base + (4 * m + 3) * 64 + lane] * fb) * inv);
            *(ushort4*)&cg[m * 8 + hi * 4] = o0;
            ushort4 o1;
            o1.x = f2bf((ca1[4 * m + 0] * fa + mg[base + (16 + 4 * m + 0) * 64 + lane] * fb) * inv);
            o1.y = f2bf((ca1[4 * m + 1] * fa + mg[base + (16 + 4 * m + 1) * 64 + lane] * fb) * inv);
            o1.z = f2bf((ca1[4 * m + 2] * fa + mg[base + (16 + 4 * m + 2) * 64 + lane] * fb) * inv);
            o1.w = f2bf((ca1[4 * m + 3] * fa + mg[base + (16 + 4 * m + 3) * 64 + lane] * fb) * inv);
            *(ushort4*)&cg[32 + m * 8 + hi * 4] = o1;
        }
    }
}

// ---------------- launcher ----------------
extern "C" void kernel_launch(void* const* d_in, const int* in_sizes, int n_in,
                              void* d_out, int out_size, void* d_ws, size_t ws_size,
                              hipStream_t stream) {
    const float* hs  = (const float*)d_in[0];
    const float* msk = (const float*)d_in[1];
    const float* Wq  = (const float*)d_in[2];
    const float* bq  = (const float*)d_in[3];
    const float* Wk  = (const float*)d_in[4];
    const float* bk  = (const float*)d_in[5];
    const float* Wv  = (const float*)d_in[6];
    const float* bv  = (const float*)d_in[7];
    const float* Wo  = (const float*)d_in[8];
    const float* bo  = (const float*)d_in[9];
    const float* rel = (const float*)d_in[10];
    float* out = (float*)d_out;

    char* ws = (char*)d_ws;
    unsigned short* hsb = (unsigned short*)ws; ws += (size_t)M_ * HID_ * 2;
    unsigned short* Wqt = (unsigned short*)ws; ws += (size_t)HID_ * HID_ * 2;
    unsigned short* Wkt = (unsigned short*)ws; ws += (size_t)HID_ * HID_ * 2;
    unsigned short* Wvt = (unsigned short*)ws; ws += (size_t)HID_ * HID_ * 2;
    unsigned short* Wot = (unsigned short*)ws; ws += (size_t)HID_ * HID_ * 2;
    unsigned short* Qb  = (unsigned short*)ws; ws += (size_t)M_ * HID_ * 2;
    unsigned short* Kb  = (unsigned short*)ws; ws += (size_t)M_ * HID_ * 2;
    unsigned short* Vtb = (unsigned short*)ws; ws += (size_t)M_ * HID_ * 2;
    unsigned short* ctxb= (unsigned short*)ws; ws += (size_t)M_ * HID_ * 2;
    unsigned* maskbits  = (unsigned*)ws;       ws += (size_t)B_ * 64 * 4;

    k_cast_hs<<<(M_ * HID_ / 4 + 255) / 256, 256, 0, stream>>>(
        hs, hsb, M_ * HID_ / 4, msk, maskbits);
    k_transpose_w4<<<dim3(16, 16, 4), 256, 0, stream>>>(Wq, Wk, Wv, Wo, Wqt, Wkt, Wvt, Wot);
    k_gemm_qkv<<<dim3(64, 12), 256, 0, stream>>>(
        hsb, Wqt, Wkt, Wvt, bq, bk, bv, Qb, Kb, Vtb);
    k_flash<<<512, 512, 0, stream>>>(Qb, Kb, Vtb, rel, maskbits, ctxb);
    k_gemm_out<<<dim3(64, 4), 512, 0, stream>>>(ctxb, Wot, bo, out);
}

// Round 17
// 103.243 us; speedup vs baseline: 1.0480x; 1.0192x over previous
//
#include <hip/hip_runtime.h>
#include <hip/hip_bf16.h>

#define B_    4
#define S_    2048
#define HID_  512
#define NH_   8
#define HD_   64
#define MAXREL 512
#define M_    (B_ * S_)   // 8192 tokens

#define LOG2E 1.44269504f
#define SCALE_Q (0.125f * LOG2E)   // folded into Q at projection time

typedef __attribute__((ext_vector_type(8))) short bf8;            // 8 bf16 (MFMA A/B frag)
typedef __attribute__((ext_vector_type(4))) float f4;             // 16x16 C/D frag
typedef __attribute__((ext_vector_type(16))) float f16f;          // 32x32 C/D frag

static __device__ __forceinline__ unsigned short f2bf(float f) {
    union { float f; unsigned int u; } v; v.f = f;
    unsigned int u = v.u;
    unsigned int r = (u + 0x7FFFu + ((u >> 16) & 1u)) >> 16;   // round-nearest-even
    return (unsigned short)r;
}

static __device__ __forceinline__ float ex2(float x) {   // raw v_exp_f32 (base-2)
    float r; asm("v_exp_f32 %0, %1" : "=v"(r) : "v"(x)); return r;
}

// async global->LDS, 16B per lane; dest = wave-uniform base + lane*16 (linear)
static __device__ __forceinline__ void gload16(const void* g, void* l) {
    __builtin_amdgcn_global_load_lds(
        (const __attribute__((address_space(1))) unsigned int*)g,
        (__attribute__((address_space(3))) unsigned int*)l, 16, 0, 0);
}

static __device__ __forceinline__ bf8 mkbf8(unsigned a, unsigned b, unsigned c, unsigned d) {
    uint4 u = make_uint4(a, b, c, d);
    return *(bf8*)&u;
}

#define MFMA16(a, b, c) __builtin_amdgcn_mfma_f32_16x16x32_bf16((a), (b), (c), 0, 0, 0)
#define MFMA32(a, b, c) __builtin_amdgcn_mfma_f32_32x32x16_bf16((a), (b), (c), 0, 0, 0)

// ---------------- fused preprocessing: hs cast + 4 weight transposes + mask bit-pack ----------------
// blocks [0, 4096): cast hs (fp32->bf16, float4-vectorized); block 0 also packs mask bits.
// blocks [4096, 5120): transpose+cast weights via LDS 32x32 tiles (z = (bid-4096)>>8).
__global__ void k_prep(const float* __restrict__ src, unsigned short* __restrict__ dst,
                       const float* __restrict__ mask, unsigned* __restrict__ maskbits,
                       const float* __restrict__ W0, const float* __restrict__ W1,
                       const float* __restrict__ W2, const float* __restrict__ W3,
                       unsigned short* __restrict__ T0, unsigned short* __restrict__ T1,
                       unsigned short* __restrict__ T2, unsigned short* __restrict__ T3) {
    __shared__ float tile[32][33];
    const int bid = blockIdx.x;
    if (bid < 4096) {
        int i = bid * 256 + threadIdx.x;
        float4 v = ((const float4*)src)[i];
        ushort4 o;
        o.x = f2bf(v.x); o.y = f2bf(v.y); o.z = f2bf(v.z); o.w = f2bf(v.w);
        ((ushort4*)dst)[i] = o;
        if (bid == 0) {
            const int t = threadIdx.x;
            const int b = t >> 6, wd = t & 63;
            unsigned bits = 0;
            #pragma unroll
            for (int j = 0; j < 32; ++j)
                bits |= (mask[b * S_ + wd * 32 + j] > 0.5f ? 1u : 0u) << j;
            maskbits[t] = bits;
        }
        return;
    }
    const int wb = bid - 4096;                  // 0..1023
    const int z = wb >> 8;                      // weight index
    const int cell = wb & 255;                  // 16x16 tile grid
    const float* W = (z == 0) ? W0 : (z == 1) ? W1 : (z == 2) ? W2 : W3;
    unsigned short* T = (z == 0) ? T0 : (z == 1) ? T1 : (z == 2) ? T2 : T3;
    const int tx = threadIdx.x & 31, ty = threadIdx.x >> 5;
    const int n0 = (cell & 15) * 32, k0 = (cell >> 4) * 32;
    #pragma unroll
    for (int i = 0; i < 4; ++i)
        tile[ty + i * 8][tx] = W[(size_t)(k0 + ty + i * 8) * HID_ + n0 + tx];
    __syncthreads();
    #pragma unroll
    for (int i = 0; i < 4; ++i)
        T[(size_t)(n0 + ty + i * 8) * HID_ + k0 + tx] = f2bf(tile[tx][ty + i * 8]);
}

// ---------------- fused QKV GEMM: 128x128 tile, dbuf LDS via global_load_lds ----------------
__global__ __launch_bounds__(256, 3) void k_gemm_qkv(
    const unsigned short* __restrict__ Abf,
    const unsigned short* __restrict__ Wqt, const unsigned short* __restrict__ Wkt,
    const unsigned short* __restrict__ Wvt,
    const float* __restrict__ bq, const float* __restrict__ bk, const float* __restrict__ bv,
    unsigned short* __restrict__ Q, unsigned short* __restrict__ K, unsigned short* __restrict__ Vt)
{
    __shared__ unsigned short Al[2][128 * 32];
    __shared__ unsigned short Bl[2][128 * 32];

    const int t = threadIdx.x;
    const int lane = t & 63, w = t >> 6;
    const int lr = lane & 15, lg = lane >> 4;
    const int wr = w >> 1, wc = w & 1;

    const int m0 = blockIdx.x * 128;
    const int ng = blockIdx.y * 128;
    const int z = ng >> 9;
    const int n0 = ng & 511;
    const unsigned short* Wt = (z == 0) ? Wqt : ((z == 1) ? Wkt : Wvt);
    const float* bias = (z == 0) ? bq : ((z == 1) ? bk : bv);
    const float osc = (z == 0) ? SCALE_Q : 1.0f;

    const int srow = t >> 2;
    const int sc = (((t & 3) ^ ((srow >> 1) & 3))) * 8;     // swizzled source col
    const unsigned short* Ag0 = &Abf[(size_t)(m0 + srow) * HID_ + sc];
    const unsigned short* Ag1 = &Abf[(size_t)(m0 + 64 + srow) * HID_ + sc];
    const unsigned short* Bg0 = &Wt[(size_t)(n0 + srow) * HID_ + sc];
    const unsigned short* Bg1 = &Wt[(size_t)(n0 + 64 + srow) * HID_ + sc];
    char* dA0 = (char*)&Al[0][0] + w * 1024;
    char* dB0 = (char*)&Bl[0][0] + w * 1024;

    const int fx = (lr >> 1) & 3;
    int aoff[4], boff[4];
    #pragma unroll
    for (int i = 0; i < 4; ++i) {
        aoff[i] = (wr * 64 + i * 16 + lr) * 32 + ((lg ^ fx) * 8);
        boff[i] = (wc * 64 + i * 16 + lr) * 32 + ((lg ^ fx) * 8);
    }

    gload16(Ag0, dA0);
    gload16(Ag1, dA0 + 4096);
    gload16(Bg0, dB0);
    gload16(Bg1, dB0 + 4096);
    __syncthreads();

    f4 acc[4][4] = {};
    for (int kt = 0; kt < 16; ++kt) {
        const int cur = kt & 1;
        if (kt < 15) {
            const int ko = (kt + 1) * 32;
            const int bo = (cur ^ 1) * 8192;
            gload16(Ag0 + ko, dA0 + bo);
            gload16(Ag1 + ko, dA0 + bo + 4096);
            gload16(Bg0 + ko, dB0 + bo);
            gload16(Bg1 + ko, dB0 + bo + 4096);
        }
        bf8 af[4], bf_[4];
        #pragma unroll
        for (int i = 0; i < 4; ++i) {
            af[i]  = *(const bf8*)&Al[cur][aoff[i]];
            bf_[i] = *(const bf8*)&Bl[cur][boff[i]];
        }
        #pragma unroll
        for (int mi = 0; mi < 4; ++mi)
            #pragma unroll
            for (int ni = 0; ni < 4; ++ni)
                acc[mi][ni] = MFMA16(af[mi], bf_[ni], acc[mi][ni]);
        __syncthreads();
    }

    #pragma unroll
    for (int mi = 0; mi < 4; ++mi)
    #pragma unroll
    for (int ni = 0; ni < 4; ++ni) {
        const int col = n0 + wc * 64 + ni * 16 + lr;
        const int h = col >> 6, d = col & 63;
        const float bs = bias[col];
        const int row0 = m0 + wr * 64 + mi * 16 + lg * 4;
        const int b = row0 >> 11, s0 = row0 & 2047;
        if (z == 2) {
            ushort4 o;
            o.x = f2bf(acc[mi][ni][0] + bs);
            o.y = f2bf(acc[mi][ni][1] + bs);
            o.z = f2bf(acc[mi][ni][2] + bs);
            o.w = f2bf(acc[mi][ni][3] + bs);
            *(ushort4*)&Vt[(((size_t)(b * NH_ + h)) * HD_ + d) * S_ + s0] = o;
        } else {
            unsigned short* dst = (z == 0) ? Q : K;
            #pragma unroll
            for (int r = 0; r < 4; ++r) {
                float v = (acc[mi][ni][r] + bs) * osc;
                dst[(((size_t)(b * NH_ + h)) * S_ + s0 + r) * HD_ + d] = f2bf(v);
            }
        }
    }
}

// ---------------- output projection GEMM: 128x128 tile, 512 threads ----------------
__global__ __launch_bounds__(512) void k_gemm_out(
    const unsigned short* __restrict__ Abf,
    const unsigned short* __restrict__ Wot,
    const float* __restrict__ bo,
    float* __restrict__ out)
{
    __shared__ unsigned short Al[2][128 * 32];
    __shared__ unsigned short Bl[2][128 * 32];

    const int t = threadIdx.x;
    const int lane = t & 63, w = t >> 6;          // 8 waves, 2x4
    const int lr = lane & 15, lg = lane >> 4;
    const int wr = w >> 2, wc = w & 3;

    const int m0 = blockIdx.x * 128;
    const int n0 = blockIdx.y * 128;

    const int srow = t >> 2;
    const int sc = (((t & 3) ^ ((srow >> 1) & 3))) * 8;
    const unsigned short* Ag = &Abf[(size_t)(m0 + srow) * HID_ + sc];
    const unsigned short* Bg = &Wot[(size_t)(n0 + srow) * HID_ + sc];
    char* dA = (char*)&Al[0][0] + w * 1024;
    char* dB = (char*)&Bl[0][0] + w * 1024;

    const int fx = (lr >> 1) & 3;
    int aoff[4], boff[2];
    #pragma unroll
    for (int i = 0; i < 4; ++i)
        aoff[i] = (wr * 64 + i * 16 + lr) * 32 + ((lg ^ fx) * 8);
    #pragma unroll
    for (int i = 0; i < 2; ++i)
        boff[i] = (wc * 32 + i * 16 + lr) * 32 + ((lg ^ fx) * 8);

    gload16(Ag, dA);
    gload16(Bg, dB);
    __syncthreads();

    f4 acc[4][2] = {};
    for (int kt = 0; kt < 16; ++kt) {
        const int cur = kt & 1;
        if (kt < 15) {
            const int ko = (kt + 1) * 32;
            const int bo_ = (cur ^ 1) * 8192;
            gload16(Ag + ko, dA + bo_);
            gload16(Bg + ko, dB + bo_);
        }
        bf8 af[4], bf_[2];
        #pragma unroll
        for (int i = 0; i < 4; ++i) af[i] = *(const bf8*)&Al[cur][aoff[i]];
        #pragma unroll
        for (int i = 0; i < 2; ++i) bf_[i] = *(const bf8*)&Bl[cur][boff[i]];
        #pragma unroll
        for (int mi = 0; mi < 4; ++mi)
            #pragma unroll
            for (int ni = 0; ni < 2; ++ni)
                acc[mi][ni] = MFMA16(af[mi], bf_[ni], acc[mi][ni]);
        __syncthreads();
    }

    #pragma unroll
    for (int mi = 0; mi < 4; ++mi)
    #pragma unroll
    for (int ni = 0; ni < 2; ++ni) {
        const int col = n0 + wc * 32 + ni * 16 + lr;
        const float bs = bo[col];
        const int row0 = m0 + wr * 64 + mi * 16 + lg * 4;
        #pragma unroll
        for (int r = 0; r < 4; ++r)
            out[(size_t)(row0 + r) * HID_ + col] = acc[mi][ni][r] + bs;
    }
}

// ---------------- flash attention: 8 waves = 4 q-groups x 2 kv-halves, mfma 32x32x16.
//   R14 structure: 3-buf KV ring (counted vmcnt), register-bitmask mask fast path,
//   pre-clipped bias window, permlane P, defer-max speculative exp, LDS pair-merge. ----------------
__global__ __launch_bounds__(512, 4) void k_flash(
    const unsigned short* __restrict__ Q, const unsigned short* __restrict__ K,
    const unsigned short* __restrict__ Vt,
    const float* __restrict__ rel_table, const unsigned* __restrict__ maskbits,
    unsigned short* __restrict__ ctx)
{
    __shared__ unsigned short KV[3][8192];   // per buf: [0,4096) ushorts K, [4096,8192) V
    __shared__ float Tw[1216];               // bias window, rel in [-605,605], pre-clipped, *log2e

    const int t = threadIdx.x;
    const int lane = t & 63, w = t >> 6;     // 8 waves
    const int q = lane & 31, hi = lane >> 5;
    const int g = w & 3, kvh = w >> 2;       // q-group, kv-half

    // bijective XCD swizzle: each XCD owns 4 complete (b,h) pairs
    const int flat = blockIdx.x;             // 0..511
    const int idx = flat >> 3;
    const int bh = (flat & 7) * 4 + (idx >> 4);
    const int qb = idx & 15;
    const int b = bh >> 3, h = bh & 7;
    const int q0 = qb * 128;

    // mask words for this wave's kv windows: lane ti (<32) holds word for tile ti
    unsigned mword = 0xFFFFFFFFu;
    if (lane < 32) mword = maskbits[b * 64 + 2 * lane + kvh];

    for (int i = t; i < 1216; i += 512) {
        int r = i - 606;
        r = r < -MAXREL ? -MAXREL : (r > MAXREL ? MAXREL : r);
        Tw[i] = rel_table[(r + MAXREL) * NH_ + h] * LOG2E;
    }
    const float TbLo = rel_table[h] * LOG2E;                    // rel = -512
    const float TbHi = rel_table[2 * MAXREL * NH_ + h] * LOG2E; // rel = +512

    const unsigned short* Kb = K + (size_t)bh * S_ * HD_;
    const unsigned short* Vb = Vt + (size_t)bh * HD_ * S_;

    const int myq = q0 + g * 32 + q;
    const int qw = q0 + g * 32;
    bf8 qf[4];   // B-frag: col=q, k(d)=16s+8hi+j
    #pragma unroll
    for (int s = 0; s < 4; ++s)
        qf[s] = *(const bf8*)&Q[((size_t)bh * S_ + myq) * HD_ + s * 16 + hi * 8];

    // staging (512 thr): thread t -> row t>>3 (0..63), slot t&7; source col pre-swizzled
    const int srow = t >> 3, sslot = t & 7;
    const int sxor = (sslot ^ (srow & 7)) * 8;
    const size_t kb0 = (size_t)srow * HD_ + sxor;
    const size_t vb0 = (size_t)srow * S_ + sxor;
    const int woff = w * 1024;               // wave's linear 1KB chunk (8 rows x 128B)

    auto stage = [&](int kvt, int buf) {
        char* base = (char*)&KV[buf][0];
        gload16(&Kb[kb0 + (size_t)kvt * 64 * HD_], base + woff);
        gload16(&Vb[vb0 + (size_t)kvt * 64], base + 8192 + woff);
    };

    f16f ca0 = {}, ca1 = {};       // ctx^T partial: col=q, d = {0,32} + (reg&3)+8*(reg>>2)+4hi
    float m_s = -INFINITY, lsum = 0.f;

    // prologue: 2 tiles in flight (2 loads/wave each)
    stage(0, 0);
    stage(1, 1);
    asm volatile("s_waitcnt lgkmcnt(0)" ::: "memory");   // Tw ds_writes drained
    asm volatile("s_waitcnt vmcnt(2)" ::: "memory");     // buf0 ready
    __builtin_amdgcn_s_barrier();
    __builtin_amdgcn_sched_barrier(0);

    const int xq = q & 7;
    // Tw index: 606 + key - myq; key = kv0 + 32*kvh + 8m + 4hi + r
    const int jb0 = 606 + 32 * kvh + 4 * hi - q0 - g * 32 - q;   // + kv0 + 8m + r
    for (int ti = 0; ti < 32; ++ti) {
        const int kv0 = ti * 64;
        const int cur = ti % 3;
        const int kvs = kv0 + 32 * kvh;      // this wave's 32-key window

        if (ti < 30) stage(ti + 2, (ti + 2) % 3);

        const unsigned short* Kt  = &KV[cur][0];
        const unsigned short* Vtl = &KV[cur][4096];

        // ---- QK^T (swapped): C[key_local][q], this wave's 32 keys ----
        f16f sa = {};
        __builtin_amdgcn_s_setprio(1);
        #pragma unroll
        for (int s = 0; s < 4; ++s) {
            bf8 kf = *(const bf8*)&Kt[(32 * kvh + q) * 64 + (((2 * s + hi) ^ xq) * 8)];
            sa = MFMA32(kf, qf[s], sa);
        }
        __builtin_amdgcn_s_setprio(0);

        // ---- mask (rare slow path; scalar-uniform skip when all-attend) ----
        const unsigned mws = __builtin_amdgcn_readlane(mword, ti);
        if (mws != 0xFFFFFFFFu) {
            #pragma unroll
            for (int m = 0; m < 4; ++m) {
                const unsigned tb = mws >> (8 * m + 4 * hi);
                #pragma unroll
                for (int r = 0; r < 4; ++r)
                    sa[4 * m + r] += ((tb >> r) & 1) ? 0.f : -3.0e38f;
            }
        }

        // ---- bias + row max (4 parallel max accumulators) ----
        float t0 = -INFINITY, t1 = -INFINITY, t2 = -INFINITY, t3 = -INFINITY;
        {
            const bool ulo = (kvs + 31 - qw <= -MAXREL);
            const bool uhi = (kvs - (qw + 31) >= MAXREL);
            if (ulo || uhi) {
                const float bc = ulo ? TbLo : TbHi;
                #pragma unroll
                for (int m = 0; m < 4; ++m) {
                    float s0 = sa[4 * m + 0] + bc;  sa[4 * m + 0] = s0;  t0 = fmaxf(t0, s0);
                    float s1 = sa[4 * m + 1] + bc;  sa[4 * m + 1] = s1;  t1 = fmaxf(t1, s1);
                    float s2 = sa[4 * m + 2] + bc;  sa[4 * m + 2] = s2;  t2 = fmaxf(t2, s2);
                    float s3 = sa[4 * m + 3] + bc;  sa[4 * m + 3] = s3;  t3 = fmaxf(t3, s3);
                }
            } else {
                #pragma unroll
                for (int m = 0; m < 4; ++m) {
                    const int jb = jb0 + kv0 + m * 8;
                    float s0 = sa[4 * m + 0] + Tw[jb + 0];  sa[4 * m + 0] = s0;  t0 = fmaxf(t0, s0);
                    float s1 = sa[4 * m + 1] + Tw[jb + 1];  sa[4 * m + 1] = s1;  t1 = fmaxf(t1, s1);
                    float s2 = sa[4 * m + 2] + Tw[jb + 2];  sa[4 * m + 2] = s2;  t2 = fmaxf(t2, s2);
                    float s3 = sa[4 * m + 3] + Tw[jb + 3];  sa[4 * m + 3] = s3;  t3 = fmaxf(t3, s3);
                }
            }
        }
        float tmaxl = fmaxf(fmaxf(t0, t1), fmaxf(t2, t3));
        const float tmax = fmaxf(tmaxl, __shfl_xor(tmaxl, 32));   // row = lanes q, q+32

        // ---- speculative exp with current m_s (defer-max common case) ----
        float ptile = 0.f;
        unsigned int pk[8];
        #pragma unroll
        for (int m = 0; m < 4; ++m) {
            float a0 = ex2(sa[4 * m + 0] - m_s), a1 = ex2(sa[4 * m + 1] - m_s);
            float a2 = ex2(sa[4 * m + 2] - m_s), a3 = ex2(sa[4 * m + 3] - m_s);
            ptile += (a0 + a1) + (a2 + a3);
            asm("v_cvt_pk_bf16_f32 %0, %1, %2" : "=v"(pk[2 * m])     : "v"(a0), "v"(a1));
            asm("v_cvt_pk_bf16_f32 %0, %1, %2" : "=v"(pk[2 * m + 1]) : "v"(a2), "v"(a3));
        }
        if (!__all(tmax <= m_s + 8.0f)) {     // rare: rescale + recompute
            const float mnew = fmaxf(m_s, tmax);
            const float fac = ex2(m_s - mnew);
            lsum *= fac;
            ca0 *= fac;
            ca1 *= fac;
            ptile = 0.f;
            #pragma unroll
            for (int m = 0; m < 4; ++m) {
                float a0 = ex2(sa[4 * m + 0] - mnew), a1 = ex2(sa[4 * m + 1] - mnew);
                float a2 = ex2(sa[4 * m + 2] - mnew), a3 = ex2(sa[4 * m + 3] - mnew);
                ptile += (a0 + a1) + (a2 + a3);
                asm("v_cvt_pk_bf16_f32 %0, %1, %2" : "=v"(pk[2 * m])     : "v"(a0), "v"(a1));
                asm("v_cvt_pk_bf16_f32 %0, %1, %2" : "=v"(pk[2 * m + 1]) : "v"(a2), "v"(a3));
            }
            m_s = mnew;
        }
        lsum += ptile;

        // ---- P B-frags via permlane32_swap (kv-local [0,32)) ----
        bf8 pf0, pf1;
        {
            unsigned c0 = pk[0], c2 = pk[2], c1 = pk[1], c3 = pk[3];
            asm("v_permlane32_swap_b32 %0, %1" : "+v"(c0), "+v"(c2));
            asm("v_permlane32_swap_b32 %0, %1" : "+v"(c1), "+v"(c3));
            pf0 = mkbf8(c0, c1, c2, c3);
        }
        {
            unsigned c0 = pk[4], c2 = pk[6], c1 = pk[5], c3 = pk[7];
            asm("v_permlane32_swap_b32 %0, %1" : "+v"(c0), "+v"(c2));
            asm("v_permlane32_swap_b32 %0, %1" : "+v"(c1), "+v"(c3));
            pf1 = mkbf8(c0, c1, c2, c3);
        }

        // ---- PV (swapped): C[d][q] += mfma32(V^T frag, P frag), kv = this half ----
        __builtin_amdgcn_s_setprio(1);
        #pragma unroll
        for (int s = 0; s < 2; ++s) {
            const int slot = ((4 * kvh + 2 * s + hi) ^ xq) * 8;
            bf8 v0 = *(const bf8*)&Vtl[q * 64 + slot];
            bf8 v1 = *(const bf8*)&Vtl[(q + 32) * 64 + slot];
            bf8 pf = (s == 0) ? pf0 : pf1;
            ca0 = MFMA32(v0, pf, ca0);
            ca1 = MFMA32(v1, pf, ca1);
        }
        __builtin_amdgcn_s_setprio(0);

        // ---- counted-vmcnt barrier ----
        if (ti < 31) {
            if (ti < 30) asm volatile("s_waitcnt vmcnt(2)" ::: "memory");
            else         asm volatile("s_waitcnt vmcnt(0)" ::: "memory");
            __builtin_amdgcn_s_barrier();
            __builtin_amdgcn_sched_barrier(0);
        }
    }

    // ---- reduce l across the lane pair (q, q+32) ----
    lsum += __shfl_xor(lsum, 32);

    // ---- pair-merge through LDS (overlay on KV ring) ----
    __syncthreads();                          // all waves done with the ring
    float* mg = (float*)&KV[0][0];            // [4 pairs][34][64] floats = 34.8 KB
    if (kvh == 1) {                           // writers: upper-half waves
        const int base = g * 34 * 64;
        #pragma unroll
        for (int j = 0; j < 16; ++j) mg[base + j * 64 + lane] = ca0[j];
        #pragma unroll
        for (int j = 0; j < 16; ++j) mg[base + (16 + j) * 64 + lane] = ca1[j];
        mg[base + 32 * 64 + lane] = m_s;
        mg[base + 33 * 64 + lane] = lsum;
    }
    __syncthreads();
    if (kvh == 0) {                           // readers: merge + epilogue
        const int base = g * 34 * 64;
        const float pm = mg[base + 32 * 64 + lane];
        const float pl = mg[base + 33 * 64 + lane];
        const float mm = fmaxf(m_s, pm);
        const float fa = ex2(m_s - mm);
        const float fb = ex2(pm - mm);
        const float lm = lsum * fa + pl * fb;
        const float inv = 1.0f / lm;
        unsigned short* cg = &ctx[(size_t)(b * S_ + myq) * HID_ + h * HD_];
        #pragma unroll
        for (int m = 0; m < 4; ++m) {
            ushort4 o0;
            o0.x = f2bf((ca0[4 * m + 0] * fa + mg[base + (4 * m + 0) * 64 + lane] * fb) * inv);
            o0.y = f2bf((ca0[4 * m + 1] * fa + mg[base + (4 * m + 1) * 64 + lane] * fb) * inv);
            o0.z = f2bf((ca0[4 * m + 2] * fa + mg[base + (4 * m + 2) * 64 + lane] * fb) * inv);
            o0.w = f2bf((ca0[4 * m + 3] * fa + mg[base + (4 * m + 3) * 64 + lane] * fb) * inv);
            *(ushort4*)&cg[m * 8 + hi * 4] = o0;
            ushort4 o1;
            o1.x = f2bf((ca1[4 * m + 0] * fa + mg[base + (16 + 4 * m + 0) * 64 + lane] * fb) * inv);
            o1.y = f2bf((ca1[4 * m + 1] * fa + mg[base + (16 + 4 * m + 1) * 64 + lane] * fb) * inv);
            o1.z = f2bf((ca1[4 * m + 2] * fa + mg[base + (16 + 4 * m + 2) * 64 + lane] * fb) * inv);
            o1.w = f2bf((ca1[4 * m + 3] * fa + mg[base + (16 + 4 * m + 3) * 64 + lane] * fb) * inv);
            *(ushort4*)&cg[32 + m * 8 + hi * 4] = o1;
        }
    }
}

// ---------------- launcher ----------------
extern "C" void kernel_launch(void* const* d_in, const int* in_sizes, int n_in,
                              void* d_out, int out_size, void* d_ws, size_t ws_size,
                              hipStream_t stream) {
    const float* hs  = (const float*)d_in[0];
    const float* msk = (const float*)d_in[1];
    const float* Wq  = (const float*)d_in[2];
    const float* bq  = (const float*)d_in[3];
    const float* Wk  = (const float*)d_in[4];
    const float* bk  = (const float*)d_in[5];
    const float* Wv  = (const float*)d_in[6];
    const float* bv  = (const float*)d_in[7];
    const float* Wo  = (const float*)d_in[8];
    const float* bo  = (const float*)d_in[9];
    const float* rel = (const float*)d_in[10];
    float* out = (float*)d_out;

    char* ws = (char*)d_ws;
    unsigned short* hsb = (unsigned short*)ws; ws += (size_t)M_ * HID_ * 2;
    unsigned short* Wqt = (unsigned short*)ws; ws += (size_t)HID_ * HID_ * 2;
    unsigned short* Wkt = (unsigned short*)ws; ws += (size_t)HID_ * HID_ * 2;
    unsigned short* Wvt = (unsigned short*)ws; ws += (size_t)HID_ * HID_ * 2;
    unsigned short* Wot = (unsigned short*)ws; ws += (size_t)HID_ * HID_ * 2;
    unsigned short* Qb  = (unsigned short*)ws; ws += (size_t)M_ * HID_ * 2;
    unsigned short* Kb  = (unsigned short*)ws; ws += (size_t)M_ * HID_ * 2;
    unsigned short* Vtb = (unsigned short*)ws; ws += (size_t)M_ * HID_ * 2;
    unsigned short* ctxb= (unsigned short*)ws; ws += (size_t)M_ * HID_ * 2;
    unsigned* maskbits  = (unsigned*)ws;       ws += (size_t)B_ * 64 * 4;

    k_prep<<<5120, 256, 0, stream>>>(hs, hsb, msk, maskbits,
                                     Wq, Wk, Wv, Wo, Wqt, Wkt, Wvt, Wot);
    k_gemm_qkv<<<dim3(64, 12), 256, 0, stream>>>(
        hsb, Wqt, Wkt, Wvt, bq, bk, bv, Qb, Kb, Vtb);
    k_flash<<<512, 512, 0, stream>>>(Qb, Kb, Vtb, rel, maskbits, ctxb);
    k_gemm_out<<<dim3(64, 4), 512, 0, stream>>>(ctxb, Wot, bo, out);
}